// Round 2
// baseline (1299.927 us; speedup 1.0000x reference)
//
#include <hip/hip_runtime.h>

#define NN 50000
#define NE 800000
#define INC 128
#define HIDC 256
#define OUTC 128
#define BN_EPS 1e-5f

__device__ __forceinline__ void atomAddF(float* p, float v) {
    unsafeAtomicAdd(p, v);  // HW global_atomic_add_f32 on gfx950, device scope
}

// ---- Layer-1 scatter: agg[dst][c] += x[src][c], plus degree count ----
__global__ __launch_bounds__(256) void k_scatter1(const float* __restrict__ x,
                                                  const int* __restrict__ ei,
                                                  float* __restrict__ agg,
                                                  int* __restrict__ cnt) {
    unsigned gid = blockIdx.x * 256u + threadIdx.x;
    if (gid >= (unsigned)NE * 128u) return;
    unsigned e = gid >> 7, c = gid & 127u;
    int src = ei[e];
    int dst = ei[NE + e];
    atomAddF(&agg[(unsigned)dst * INC + c], x[(unsigned)src * INC + c]);
    if (c == 0u) atomicAdd(&cnt[dst], 1);
}

// ---- Layer-2 scatter: agg[dst][c] += h[src][c] ----
__global__ __launch_bounds__(256) void k_scatter2(const float* __restrict__ h,
                                                  const int* __restrict__ ei,
                                                  float* __restrict__ agg) {
    unsigned gid = blockIdx.x * 256u + threadIdx.x;
    if (gid >= (unsigned)NE * 256u) return;
    unsigned e = gid >> 8, c = gid & 255u;
    int src = ei[e];
    int dst = ei[NE + e];
    atomAddF(&agg[(unsigned)dst * HIDC + c], h[(unsigned)src * HIDC + c]);
}

// ---- 1/max(cnt,1) ----
__global__ void k_invc(const int* __restrict__ cnt, float* __restrict__ invc) {
    int i = blockIdx.x * 256 + threadIdx.x;
    if (i < NN) invc[i] = 1.0f / fmaxf((float)cnt[i], 1.0f);
}

// ---- Generic fused GEMM: out = [A1*invc | A2] @ [W1 ; W2] + bias ----
// Block tile 64 rows x 64 cols, 256 threads, 4x4 per-thread tile, BK=32.
template <int K1, int K2, int NC>
__global__ __launch_bounds__(256) void k_gemm(const float* __restrict__ A1,
                                              const float* __restrict__ invc,
                                              const float* __restrict__ A2,
                                              const float* __restrict__ W1,
                                              const float* __restrict__ W2,
                                              const float* __restrict__ bias,
                                              float* __restrict__ out, int M) {
    __shared__ float As[32][68];  // transposed A tile, padded (16B-aligned rows, conflict-free)
    __shared__ float Ws[32][64];
    const int t = threadIdx.x;
    const int rr = t >> 4;  // 0..15 -> row group
    const int cr = t & 15;  // 0..15 -> col group
    const int r0 = blockIdx.x * 64;
    const int c0 = blockIdx.y * 64;
    float acc[4][4] = {};

    const int KT = K1 + K2;
    for (int kt = 0; kt < KT; kt += 32) {
        const bool ph1 = (kt < K1);
        const float* __restrict__ A = ph1 ? A1 : A2;
        const int AK = ph1 ? K1 : K2;
        const int kb = ph1 ? kt : (kt - K1);
        const float* __restrict__ W = ph1 ? W1 : W2;

        // Load A tile: 64 rows x 32 k, via float4, store transposed As[k][r]
        #pragma unroll
        for (int i = 0; i < 2; ++i) {
            int idx = i * 256 + t;      // 0..511 float4 slots
            int r = idx >> 3;           // 0..63
            int kq = idx & 7;           // float4 index along k
            int row = r0 + r;
            float4 v = make_float4(0.f, 0.f, 0.f, 0.f);
            if (row < M) {
                v = *reinterpret_cast<const float4*>(&A[(size_t)row * AK + kb + kq * 4]);
                if (ph1) {
                    float ic = invc[row];
                    v.x *= ic; v.y *= ic; v.z *= ic; v.w *= ic;
                }
            }
            As[kq * 4 + 0][r] = v.x;
            As[kq * 4 + 1][r] = v.y;
            As[kq * 4 + 2][r] = v.z;
            As[kq * 4 + 3][r] = v.w;
        }
        // Load W tile: 32 k x 64 cols
        #pragma unroll
        for (int i = 0; i < 2; ++i) {
            int idx = i * 256 + t;      // 0..511 float4 slots
            int k = idx >> 4;           // 0..31
            int cq = idx & 15;          // float4 index along cols
            float4 w = *reinterpret_cast<const float4*>(&W[(size_t)(kb + k) * NC + c0 + cq * 4]);
            *reinterpret_cast<float4*>(&Ws[k][cq * 4]) = w;
        }
        __syncthreads();

        #pragma unroll
        for (int kk = 0; kk < 32; ++kk) {
            float4 a = *reinterpret_cast<const float4*>(&As[kk][rr * 4]);
            float4 w = *reinterpret_cast<const float4*>(&Ws[kk][cr * 4]);
            float av[4] = {a.x, a.y, a.z, a.w};
            float wv[4] = {w.x, w.y, w.z, w.w};
            #pragma unroll
            for (int i = 0; i < 4; ++i)
                #pragma unroll
                for (int j = 0; j < 4; ++j)
                    acc[i][j] = fmaf(av[i], wv[j], acc[i][j]);
        }
        __syncthreads();
    }

    // Epilogue: + bias, store
    float4 b = *reinterpret_cast<const float4*>(&bias[c0 + cr * 4]);
    float bv[4] = {b.x, b.y, b.z, b.w};
    #pragma unroll
    for (int i = 0; i < 4; ++i) {
        int row = r0 + rr * 4 + i;
        if (row < M) {
            float4 o;
            o.x = acc[i][0] + bv[0];
            o.y = acc[i][1] + bv[1];
            o.z = acc[i][2] + bv[2];
            o.w = acc[i][3] + bv[3];
            *reinterpret_cast<float4*>(&out[(size_t)row * NC + c0 + cr * 4]) = o;
        }
    }
}

// ---- BN stats: per-channel sum and sumsq over rows ----
__global__ __launch_bounds__(256) void k_bnstats(const float* __restrict__ h,
                                                 float* __restrict__ sums) {
    int c = threadIdx.x;      // 0..255 = channel
    int r0 = blockIdx.x * 64;
    int r1 = min(r0 + 64, NN);
    float s = 0.f, s2 = 0.f;
    for (int r = r0; r < r1; ++r) {
        float v = h[(size_t)r * HIDC + c];
        s += v;
        s2 += v * v;
    }
    atomAddF(&sums[c], s);
    atomAddF(&sums[HIDC + c], s2);
}

__global__ void k_bnfin(const float* __restrict__ sums, const float* __restrict__ gamma,
                        const float* __restrict__ beta, float* __restrict__ sc,
                        float* __restrict__ sh) {
    int c = threadIdx.x;
    float mu = sums[c] * (1.0f / NN);
    float var = sums[HIDC + c] * (1.0f / NN) - mu * mu;
    float s = gamma[c] * rsqrtf(var + BN_EPS);
    sc[c] = s;
    sh[c] = beta[c] - mu * s;
}

// ---- BN apply + ReLU, in place over h (float4) ----
__global__ __launch_bounds__(256) void k_bnapply(float* __restrict__ h,
                                                 const float* __restrict__ sc,
                                                 const float* __restrict__ sh) {
    unsigned gid = blockIdx.x * 256u + threadIdx.x;  // float4 index
    if (gid >= (unsigned)NN * 64u) return;
    unsigned c4 = gid & 63u;
    float4 v = reinterpret_cast<float4*>(h)[gid];
    float4 a = reinterpret_cast<const float4*>(sc)[c4];
    float4 b = reinterpret_cast<const float4*>(sh)[c4];
    v.x = fmaxf(fmaf(v.x, a.x, b.x), 0.f);
    v.y = fmaxf(fmaf(v.y, a.y, b.y), 0.f);
    v.z = fmaxf(fmaf(v.z, a.z, b.z), 0.f);
    v.w = fmaxf(fmaf(v.w, a.w, b.w), 0.f);
    reinterpret_cast<float4*>(h)[gid] = v;
}

extern "C" void kernel_launch(void* const* d_in, const int* in_sizes, int n_in,
                              void* d_out, int out_size, void* d_ws, size_t ws_size,
                              hipStream_t stream) {
    const float* x     = (const float*)d_in[0];
    const int*   ei    = (const int*)d_in[1];   // [2, E] int32
    const float* W1l   = (const float*)d_in[2];
    const float* b1l   = (const float*)d_in[3];
    const float* W1r   = (const float*)d_in[4];
    const float* gam1  = (const float*)d_in[5];
    const float* bet1  = (const float*)d_in[6];
    const float* W2l   = (const float*)d_in[7];
    const float* b2l   = (const float*)d_in[8];
    const float* W2r   = (const float*)d_in[9];
    float* out = (float*)d_out;

    float* ws = (float*)d_ws;
    float* aggbuf = ws;                              // NN*256 floats (layer1 uses first NN*128)
    float* h      = ws + (size_t)NN * 256;           // NN*256 floats
    int*   cnt    = (int*)(ws + (size_t)NN * 512);   // NN ints
    float* invc   = ws + (size_t)NN * 512 + NN;      // NN floats
    float* bnsums = invc + NN;                       // 512 floats
    float* bnsc   = bnsums + 512;                    // 256
    float* bnsh   = bnsc + 256;                      // 256

    // Zero: full agg buffer + (cnt, invc, bn scratch) region
    hipMemsetAsync(aggbuf, 0, (size_t)NN * 256 * sizeof(float), stream);
    hipMemsetAsync(cnt, 0, ((size_t)NN * 2 + 1024) * sizeof(float), stream);

    // Layer 1
    k_scatter1<<<(NE * 128 + 255) / 256, 256, 0, stream>>>(x, ei, aggbuf, cnt);
    k_invc<<<(NN + 255) / 256, 256, 0, stream>>>(cnt, invc);
    k_gemm<128, 128, 256><<<dim3(782, 4), 256, 0, stream>>>(aggbuf, invc, x, W1l, W1r, b1l, h, NN);
    k_bnstats<<<782, 256, 0, stream>>>(h, bnsums);
    k_bnfin<<<1, 256, 0, stream>>>(bnsums, gam1, bet1, bnsc, bnsh);
    k_bnapply<<<(NN * 64 + 255) / 256, 256, 0, stream>>>(h, bnsc, bnsh);

    // Layer 2 (re-zero only the first NN*128 part of aggbuf; upper half still zero)
    hipMemsetAsync(aggbuf, 0, (size_t)NN * 128 * sizeof(float), stream);
    k_scatter2<<<(NE * 256 + 255) / 256, 256, 0, stream>>>(h, ei, aggbuf);
    k_gemm<256, 256, 128><<<dim3(782, 2), 256, 0, stream>>>(aggbuf, invc, h, W2l, W2r, b2l, out, NN);
}

// Round 3
// 682.165 us; speedup vs baseline: 1.9056x; 1.9056x over previous
//
#include <hip/hip_runtime.h>

#define NN 50000
#define NE 800000
#define INC 128
#define HIDC 256
#define OUTC 128
#define BN_EPS 1e-5f

__device__ __forceinline__ void atomAddF(float* p, float v) {
    unsafeAtomicAdd(p, v);  // HW global_atomic_add_f32 on gfx950
}

// ---- CSR build step 1: degree count ----
__global__ __launch_bounds__(256) void k_degree(const int* __restrict__ ei,
                                                int* __restrict__ cnt) {
    unsigned e = blockIdx.x * 256u + threadIdx.x;
    if (e >= (unsigned)NE) return;
    atomicAdd(&cnt[ei[NE + e]], 1);
}

// ---- CSR build step 2: exclusive prefix scan (single block, work-efficient) ----
// rowptr[i] = sum cnt[0..i-1]; rowptr[NN] = NE; cursor[i] = rowptr[i]; invc[i] = 1/max(cnt,1)
__global__ __launch_bounds__(1024) void k_scan(const int* __restrict__ cnt,
                                               int* __restrict__ rowptr,
                                               int* __restrict__ cursor,
                                               float* __restrict__ invc) {
    const int CH = (NN + 1023) / 1024;  // 49 elements per thread
    const int t = threadIdx.x;
    const int i0 = t * CH;
    // pass 1: per-thread chunk total
    int s = 0;
    for (int k = 0; k < CH; ++k) {
        int i = i0 + k;
        if (i < NN) s += cnt[i];
    }
    // scan thread totals (Hillis-Steele, 1024 threads)
    __shared__ int sm[1024];
    sm[t] = s;
    __syncthreads();
    for (int off = 1; off < 1024; off <<= 1) {
        int v = (t >= off) ? sm[t - off] : 0;
        __syncthreads();
        sm[t] += v;
        __syncthreads();
    }
    int run = sm[t] - s;  // exclusive prefix of this thread's chunk
    // pass 2: rescan and write
    for (int k = 0; k < CH; ++k) {
        int i = i0 + k;
        if (i < NN) {
            int v = cnt[i];
            rowptr[i] = run;
            cursor[i] = run;
            invc[i] = 1.0f / fmaxf((float)v, 1.0f);
            run += v;
        }
    }
    if (t == 1023) rowptr[NN] = sm[1023];
}

// ---- CSR build step 3: fill src lists ----
__global__ __launch_bounds__(256) void k_fill(const int* __restrict__ ei,
                                              int* __restrict__ cursor,
                                              int* __restrict__ csr_src) {
    unsigned e = blockIdx.x * 256u + threadIdx.x;
    if (e >= (unsigned)NE) return;
    int dst = ei[NE + e];
    int pos = atomicAdd(&cursor[dst], 1);
    csr_src[pos] = ei[e];
}

// ---- Gather-aggregate: one wave per dst node; agg[i][:] = mean of feat[src][:] ----
template <int C, int VEC>
__global__ __launch_bounds__(256) void k_agg(const float* __restrict__ feat,
                                             const int* __restrict__ rowptr,
                                             const int* __restrict__ csr_src,
                                             const float* __restrict__ invc,
                                             float* __restrict__ agg) {
    int gw = (blockIdx.x * 256 + threadIdx.x) >> 6;  // node = global wave id
    int lane = threadIdx.x & 63;
    if (gw >= NN) return;
    int beg = rowptr[gw], end = rowptr[gw + 1];
    float acc[VEC] = {};
    for (int e = beg; e < end; ++e) {
        int s = csr_src[e];
        const float* p = &feat[(size_t)s * C + lane * VEC];
        if constexpr (VEC == 2) {
            float2 v = *reinterpret_cast<const float2*>(p);
            acc[0] += v.x; acc[1] += v.y;
        } else {
            float4 v = *reinterpret_cast<const float4*>(p);
            acc[0] += v.x; acc[1] += v.y; acc[2] += v.z; acc[3] += v.w;
        }
    }
    float ic = invc[gw];
    float* o = &agg[(size_t)gw * C + lane * VEC];
    if constexpr (VEC == 2) {
        float2 w = make_float2(acc[0] * ic, acc[1] * ic);
        *reinterpret_cast<float2*>(o) = w;
    } else {
        float4 w = make_float4(acc[0] * ic, acc[1] * ic, acc[2] * ic, acc[3] * ic);
        *reinterpret_cast<float4*>(o) = w;
    }
}

// ---- Fused GEMM: out = A1 @ W1 + A2 @ W2 + bias ----
// Block tile 64 rows x 64 cols, 256 threads, 4x4 per-thread tile, BK=32.
template <int K1, int K2, int NC>
__global__ __launch_bounds__(256) void k_gemm(const float* __restrict__ A1,
                                              const float* __restrict__ A2,
                                              const float* __restrict__ W1,
                                              const float* __restrict__ W2,
                                              const float* __restrict__ bias,
                                              float* __restrict__ out, int M) {
    __shared__ float As[32][68];  // transposed A tile, padded
    __shared__ float Ws[32][64];
    const int t = threadIdx.x;
    const int rr = t >> 4;
    const int cr = t & 15;
    const int r0 = blockIdx.x * 64;
    const int c0 = blockIdx.y * 64;
    float acc[4][4] = {};

    const int KT = K1 + K2;
    for (int kt = 0; kt < KT; kt += 32) {
        const bool ph1 = (kt < K1);
        const float* __restrict__ A = ph1 ? A1 : A2;
        const int AK = ph1 ? K1 : K2;
        const int kb = ph1 ? kt : (kt - K1);
        const float* __restrict__ W = ph1 ? W1 : W2;

        #pragma unroll
        for (int i = 0; i < 2; ++i) {
            int idx = i * 256 + t;
            int r = idx >> 3;
            int kq = idx & 7;
            int row = r0 + r;
            float4 v = make_float4(0.f, 0.f, 0.f, 0.f);
            if (row < M)
                v = *reinterpret_cast<const float4*>(&A[(size_t)row * AK + kb + kq * 4]);
            As[kq * 4 + 0][r] = v.x;
            As[kq * 4 + 1][r] = v.y;
            As[kq * 4 + 2][r] = v.z;
            As[kq * 4 + 3][r] = v.w;
        }
        #pragma unroll
        for (int i = 0; i < 2; ++i) {
            int idx = i * 256 + t;
            int k = idx >> 4;
            int cq = idx & 15;
            float4 w = *reinterpret_cast<const float4*>(&W[(size_t)(kb + k) * NC + c0 + cq * 4]);
            *reinterpret_cast<float4*>(&Ws[k][cq * 4]) = w;
        }
        __syncthreads();

        #pragma unroll
        for (int kk = 0; kk < 32; ++kk) {
            float4 a = *reinterpret_cast<const float4*>(&As[kk][rr * 4]);
            float4 w = *reinterpret_cast<const float4*>(&Ws[kk][cr * 4]);
            float av[4] = {a.x, a.y, a.z, a.w};
            float wv[4] = {w.x, w.y, w.z, w.w};
            #pragma unroll
            for (int i = 0; i < 4; ++i)
                #pragma unroll
                for (int j = 0; j < 4; ++j)
                    acc[i][j] = fmaf(av[i], wv[j], acc[i][j]);
        }
        __syncthreads();
    }

    float4 b = *reinterpret_cast<const float4*>(&bias[c0 + cr * 4]);
    float bv[4] = {b.x, b.y, b.z, b.w};
    #pragma unroll
    for (int i = 0; i < 4; ++i) {
        int row = r0 + rr * 4 + i;
        if (row < M) {
            float4 o;
            o.x = acc[i][0] + bv[0];
            o.y = acc[i][1] + bv[1];
            o.z = acc[i][2] + bv[2];
            o.w = acc[i][3] + bv[3];
            *reinterpret_cast<float4*>(&out[(size_t)row * NC + c0 + cr * 4]) = o;
        }
    }
}

// ---- BN stats: per-channel sum and sumsq over rows ----
__global__ __launch_bounds__(256) void k_bnstats(const float* __restrict__ h,
                                                 float* __restrict__ sums) {
    int c = threadIdx.x;
    int r0 = blockIdx.x * 64;
    int r1 = min(r0 + 64, NN);
    float s = 0.f, s2 = 0.f;
    for (int r = r0; r < r1; ++r) {
        float v = h[(size_t)r * HIDC + c];
        s += v;
        s2 += v * v;
    }
    atomAddF(&sums[c], s);
    atomAddF(&sums[HIDC + c], s2);
}

__global__ void k_bnfin(const float* __restrict__ sums, const float* __restrict__ gamma,
                        const float* __restrict__ beta, float* __restrict__ sc,
                        float* __restrict__ sh) {
    int c = threadIdx.x;
    float mu = sums[c] * (1.0f / NN);
    float var = sums[HIDC + c] * (1.0f / NN) - mu * mu;
    float s = gamma[c] * rsqrtf(var + BN_EPS);
    sc[c] = s;
    sh[c] = beta[c] - mu * s;
}

// ---- BN apply + ReLU, in place over h (float4) ----
__global__ __launch_bounds__(256) void k_bnapply(float* __restrict__ h,
                                                 const float* __restrict__ sc,
                                                 const float* __restrict__ sh) {
    unsigned gid = blockIdx.x * 256u + threadIdx.x;
    if (gid >= (unsigned)NN * 64u) return;
    unsigned c4 = gid & 63u;
    float4 v = reinterpret_cast<float4*>(h)[gid];
    float4 a = reinterpret_cast<const float4*>(sc)[c4];
    float4 b = reinterpret_cast<const float4*>(sh)[c4];
    v.x = fmaxf(fmaf(v.x, a.x, b.x), 0.f);
    v.y = fmaxf(fmaf(v.y, a.y, b.y), 0.f);
    v.z = fmaxf(fmaf(v.z, a.z, b.z), 0.f);
    v.w = fmaxf(fmaf(v.w, a.w, b.w), 0.f);
    reinterpret_cast<float4*>(h)[gid] = v;
}

extern "C" void kernel_launch(void* const* d_in, const int* in_sizes, int n_in,
                              void* d_out, int out_size, void* d_ws, size_t ws_size,
                              hipStream_t stream) {
    const float* x     = (const float*)d_in[0];
    const int*   ei    = (const int*)d_in[1];   // [2, E] int32
    const float* W1l   = (const float*)d_in[2];
    const float* b1l   = (const float*)d_in[3];
    const float* W1r   = (const float*)d_in[4];
    const float* gam1  = (const float*)d_in[5];
    const float* bet1  = (const float*)d_in[6];
    const float* W2l   = (const float*)d_in[7];
    const float* b2l   = (const float*)d_in[8];
    const float* W2r   = (const float*)d_in[9];
    float* out = (float*)d_out;

    float* ws = (float*)d_ws;
    float* aggbuf  = ws;                               // NN*256 f
    float* h       = aggbuf + (size_t)NN * 256;        // NN*256 f
    int*   cnt     = (int*)(h + (size_t)NN * 256);     // NN i  (zeroed)
    float* bnsums  = (float*)(cnt + NN);               // 512 f (zeroed)
    float* bnsc    = bnsums + 512;                     // 256 f
    float* bnsh    = bnsc + 256;                       // 256 f
    float* invc    = bnsh + 256;                       // NN f
    int*   rowptr  = (int*)(invc + NN);                // NN+1 i
    int*   cursor  = rowptr + NN + 1;                  // NN i
    int*   csr_src = cursor + NN;                      // NE i

    // Zero only cnt + bnsums (+bnsc/bnsh padding)
    hipMemsetAsync(cnt, 0, (NN + 1024) * sizeof(int), stream);

    // Build CSR (shared by both layers)
    k_degree<<<(NE + 255) / 256, 256, 0, stream>>>(ei, cnt);
    k_scan<<<1, 1024, 0, stream>>>(cnt, rowptr, cursor, invc);
    k_fill<<<(NE + 255) / 256, 256, 0, stream>>>(ei, cursor, csr_src);

    // Layer 1: aggregate -> fused GEMM -> BN -> ReLU
    k_agg<INC, 2><<<(NN * 64 + 255) / 256, 256, 0, stream>>>(x, rowptr, csr_src, invc, aggbuf);
    k_gemm<128, 128, 256><<<dim3(782, 4), 256, 0, stream>>>(aggbuf, x, W1l, W1r, b1l, h, NN);
    k_bnstats<<<782, 256, 0, stream>>>(h, bnsums);
    k_bnfin<<<1, 256, 0, stream>>>(bnsums, gam1, bet1, bnsc, bnsh);
    k_bnapply<<<(NN * 64 + 255) / 256, 256, 0, stream>>>(h, bnsc, bnsh);

    // Layer 2: aggregate -> fused GEMM
    k_agg<HIDC, 4><<<(NN * 64 + 255) / 256, 256, 0, stream>>>(h, rowptr, csr_src, invc, aggbuf);
    k_gemm<256, 256, 128><<<dim3(782, 2), 256, 0, stream>>>(aggbuf, h, W2l, W2r, b2l, out, NN);
}

// Round 4
// 544.267 us; speedup vs baseline: 2.3884x; 1.2534x over previous
//
#include <hip/hip_runtime.h>

#define NN 50000
#define NPAD 50176  // NN rounded up to 49*1024 for int4 scan loads
#define NE 800000
#define INC 128
#define HIDC 256
#define OUTC 128
#define BN_EPS 1e-5f

__device__ __forceinline__ void atomAddF(float* p, float v) {
    unsafeAtomicAdd(p, v);  // HW global_atomic_add_f32 on gfx950
}

// ---- CSR build step 1: degree count ----
__global__ __launch_bounds__(256) void k_degree(const int* __restrict__ ei,
                                                int* __restrict__ cnt) {
    unsigned e = blockIdx.x * 256u + threadIdx.x;
    if (e >= (unsigned)NE) return;
    atomicAdd(&cnt[ei[NE + e]], 1);
}

// ---- CSR build step 2a: per-block (1024-elem) local exclusive scan + block totals ----
__global__ __launch_bounds__(256) void k_scanA(const int* __restrict__ cnt,
                                               int* __restrict__ locpre,
                                               int* __restrict__ bsum) {
    const int b = blockIdx.x, t = threadIdx.x;
    const int base = b * 1024 + t * 4;
    int4 v = *reinterpret_cast<const int4*>(&cnt[base]);  // cnt padded to NPAD, pad=0
    int s = v.x + v.y + v.z + v.w;
    __shared__ int sm[256];
    sm[t] = s;
    __syncthreads();
    for (int off = 1; off < 256; off <<= 1) {
        int y = (t >= off) ? sm[t - off] : 0;
        __syncthreads();
        sm[t] += y;
        __syncthreads();
    }
    int excl = sm[t] - s;  // exclusive prefix of this thread within block
    locpre[base + 0] = excl;
    locpre[base + 1] = excl + v.x;
    locpre[base + 2] = excl + v.x + v.y;
    locpre[base + 3] = excl + v.x + v.y + v.z;
    if (t == 255) bsum[b] = sm[255];
}

// ---- CSR build step 2b: scan the 49 block totals (single wave, shfl) ----
__global__ __launch_bounds__(64) void k_scanB(const int* __restrict__ bsum,
                                              int* __restrict__ boff) {
    const int nb = NPAD / 1024;  // 49
    int t = threadIdx.x;
    int v = (t < nb) ? bsum[t] : 0;
    int x = v;
    #pragma unroll
    for (int off = 1; off < 64; off <<= 1) {
        int y = __shfl_up(x, off);
        if (t >= off) x += y;
    }
    boff[t] = x - v;  // exclusive
}

// ---- CSR build step 2c: add block offsets; emit rowptr/cursor/invc ----
__global__ __launch_bounds__(256) void k_scanC(const int* __restrict__ cnt,
                                               const int* __restrict__ locpre,
                                               const int* __restrict__ boff,
                                               int* __restrict__ rowptr,
                                               int* __restrict__ cursor,
                                               float* __restrict__ invc) {
    const int b = blockIdx.x, t = threadIdx.x;
    const int off = boff[b];
    const int base = b * 1024 + t * 4;
    #pragma unroll
    for (int k = 0; k < 4; ++k) {
        int i = base + k;
        if (i < NN) {
            int rp = locpre[i] + off;
            rowptr[i] = rp;
            cursor[i] = rp;
            invc[i] = 1.0f / fmaxf((float)cnt[i], 1.0f);
        }
    }
    if (b == 0 && t == 0) rowptr[NN] = NE;
}

// ---- CSR build step 3: fill src lists ----
__global__ __launch_bounds__(256) void k_fill(const int* __restrict__ ei,
                                              int* __restrict__ cursor,
                                              int* __restrict__ csr_src) {
    unsigned e = blockIdx.x * 256u + threadIdx.x;
    if (e >= (unsigned)NE) return;
    int dst = ei[NE + e];
    int pos = atomicAdd(&cursor[dst], 1);
    csr_src[pos] = ei[e];
}

// ---- Gather-aggregate: one wave per dst node; agg[i][:] = mean of feat[src][:] ----
template <int C, int VEC>
__global__ __launch_bounds__(256) void k_agg(const float* __restrict__ feat,
                                             const int* __restrict__ rowptr,
                                             const int* __restrict__ csr_src,
                                             const float* __restrict__ invc,
                                             float* __restrict__ agg) {
    int gw = (blockIdx.x * 256 + threadIdx.x) >> 6;  // node = global wave id
    int lane = threadIdx.x & 63;
    if (gw >= NN) return;
    int beg = rowptr[gw], end = rowptr[gw + 1];
    float acc[VEC] = {};
    for (int e = beg; e < end; ++e) {
        int s = csr_src[e];
        const float* p = &feat[(size_t)s * C + lane * VEC];
        if constexpr (VEC == 2) {
            float2 v = *reinterpret_cast<const float2*>(p);
            acc[0] += v.x; acc[1] += v.y;
        } else {
            float4 v = *reinterpret_cast<const float4*>(p);
            acc[0] += v.x; acc[1] += v.y; acc[2] += v.z; acc[3] += v.w;
        }
    }
    float ic = invc[gw];
    float* o = &agg[(size_t)gw * C + lane * VEC];
    if constexpr (VEC == 2) {
        float2 w = make_float2(acc[0] * ic, acc[1] * ic);
        *reinterpret_cast<float2*>(o) = w;
    } else {
        float4 w = make_float4(acc[0] * ic, acc[1] * ic, acc[2] * ic, acc[3] * ic);
        *reinterpret_cast<float4*>(o) = w;
    }
}

// ---- Fused GEMM: out = A1 @ W1 + A2 @ W2 + bias ----
// Block tile 64 rows x 64 cols, 256 threads, 4x4 per-thread tile, BK=32.
template <int K1, int K2, int NC>
__global__ __launch_bounds__(256) void k_gemm(const float* __restrict__ A1,
                                              const float* __restrict__ A2,
                                              const float* __restrict__ W1,
                                              const float* __restrict__ W2,
                                              const float* __restrict__ bias,
                                              float* __restrict__ out, int M) {
    __shared__ float As[32][68];  // transposed A tile, padded
    __shared__ float Ws[32][64];
    const int t = threadIdx.x;
    const int rr = t >> 4;
    const int cr = t & 15;
    const int r0 = blockIdx.x * 64;
    const int c0 = blockIdx.y * 64;
    float acc[4][4] = {};

    const int KT = K1 + K2;
    for (int kt = 0; kt < KT; kt += 32) {
        const bool ph1 = (kt < K1);
        const float* __restrict__ A = ph1 ? A1 : A2;
        const int AK = ph1 ? K1 : K2;
        const int kb = ph1 ? kt : (kt - K1);
        const float* __restrict__ W = ph1 ? W1 : W2;

        #pragma unroll
        for (int i = 0; i < 2; ++i) {
            int idx = i * 256 + t;
            int r = idx >> 3;
            int kq = idx & 7;
            int row = r0 + r;
            float4 v = make_float4(0.f, 0.f, 0.f, 0.f);
            if (row < M)
                v = *reinterpret_cast<const float4*>(&A[(size_t)row * AK + kb + kq * 4]);
            As[kq * 4 + 0][r] = v.x;
            As[kq * 4 + 1][r] = v.y;
            As[kq * 4 + 2][r] = v.z;
            As[kq * 4 + 3][r] = v.w;
        }
        #pragma unroll
        for (int i = 0; i < 2; ++i) {
            int idx = i * 256 + t;
            int k = idx >> 4;
            int cq = idx & 15;
            float4 w = *reinterpret_cast<const float4*>(&W[(size_t)(kb + k) * NC + c0 + cq * 4]);
            *reinterpret_cast<float4*>(&Ws[k][cq * 4]) = w;
        }
        __syncthreads();

        #pragma unroll
        for (int kk = 0; kk < 32; ++kk) {
            float4 a = *reinterpret_cast<const float4*>(&As[kk][rr * 4]);
            float4 w = *reinterpret_cast<const float4*>(&Ws[kk][cr * 4]);
            float av[4] = {a.x, a.y, a.z, a.w};
            float wv[4] = {w.x, w.y, w.z, w.w};
            #pragma unroll
            for (int i = 0; i < 4; ++i)
                #pragma unroll
                for (int j = 0; j < 4; ++j)
                    acc[i][j] = fmaf(av[i], wv[j], acc[i][j]);
        }
        __syncthreads();
    }

    float4 b = *reinterpret_cast<const float4*>(&bias[c0 + cr * 4]);
    float bv[4] = {b.x, b.y, b.z, b.w};
    #pragma unroll
    for (int i = 0; i < 4; ++i) {
        int row = r0 + rr * 4 + i;
        if (row < M) {
            float4 o;
            o.x = acc[i][0] + bv[0];
            o.y = acc[i][1] + bv[1];
            o.z = acc[i][2] + bv[2];
            o.w = acc[i][3] + bv[3];
            *reinterpret_cast<float4*>(&out[(size_t)row * NC + c0 + cr * 4]) = o;
        }
    }
}

// ---- BN stats: per-channel sum and sumsq over rows ----
__global__ __launch_bounds__(256) void k_bnstats(const float* __restrict__ h,
                                                 float* __restrict__ sums) {
    int c = threadIdx.x;
    int r0 = blockIdx.x * 64;
    int r1 = min(r0 + 64, NN);
    float s = 0.f, s2 = 0.f;
    for (int r = r0; r < r1; ++r) {
        float v = h[(size_t)r * HIDC + c];
        s += v;
        s2 += v * v;
    }
    atomAddF(&sums[c], s);
    atomAddF(&sums[HIDC + c], s2);
}

__global__ void k_bnfin(const float* __restrict__ sums, const float* __restrict__ gamma,
                        const float* __restrict__ beta, float* __restrict__ sc,
                        float* __restrict__ sh) {
    int c = threadIdx.x;
    float mu = sums[c] * (1.0f / NN);
    float var = sums[HIDC + c] * (1.0f / NN) - mu * mu;
    float s = gamma[c] * rsqrtf(var + BN_EPS);
    sc[c] = s;
    sh[c] = beta[c] - mu * s;
}

// ---- BN apply + ReLU, in place over h (float4) ----
__global__ __launch_bounds__(256) void k_bnapply(float* __restrict__ h,
                                                 const float* __restrict__ sc,
                                                 const float* __restrict__ sh) {
    unsigned gid = blockIdx.x * 256u + threadIdx.x;
    if (gid >= (unsigned)NN * 64u) return;
    unsigned c4 = gid & 63u;
    float4 v = reinterpret_cast<float4*>(h)[gid];
    float4 a = reinterpret_cast<const float4*>(sc)[c4];
    float4 b = reinterpret_cast<const float4*>(sh)[c4];
    v.x = fmaxf(fmaf(v.x, a.x, b.x), 0.f);
    v.y = fmaxf(fmaf(v.y, a.y, b.y), 0.f);
    v.z = fmaxf(fmaf(v.z, a.z, b.z), 0.f);
    v.w = fmaxf(fmaf(v.w, a.w, b.w), 0.f);
    reinterpret_cast<float4*>(h)[gid] = v;
}

extern "C" void kernel_launch(void* const* d_in, const int* in_sizes, int n_in,
                              void* d_out, int out_size, void* d_ws, size_t ws_size,
                              hipStream_t stream) {
    const float* x     = (const float*)d_in[0];
    const int*   ei    = (const int*)d_in[1];   // [2, E] int32
    const float* W1l   = (const float*)d_in[2];
    const float* b1l   = (const float*)d_in[3];
    const float* W1r   = (const float*)d_in[4];
    const float* gam1  = (const float*)d_in[5];
    const float* bet1  = (const float*)d_in[6];
    const float* W2l   = (const float*)d_in[7];
    const float* b2l   = (const float*)d_in[8];
    const float* W2r   = (const float*)d_in[9];
    float* out = (float*)d_out;

    float* ws = (float*)d_ws;
    float* aggbuf  = ws;                               // NN*256 f
    float* h       = aggbuf + (size_t)NN * 256;        // NN*256 f
    int*   cnt     = (int*)(h + (size_t)NN * 256);     // NPAD i (zeroed, incl pad)
    float* bnsums  = (float*)(cnt + NPAD);             // 512 f (zeroed)
    float* bnsc    = bnsums + 512;                     // 256 f
    float* bnsh    = bnsc + 256;                       // 256 f
    float* invc    = bnsh + 256;                       // NN f
    int*   rowptr  = (int*)(invc + NN);                // NN+1 i
    int*   cursor  = rowptr + NN + 1;                  // NN i
    int*   csr_src = cursor + NN;                      // NE i
    int*   bsum    = csr_src + NE;                     // 64 i
    int*   boff    = bsum + 64;                        // 64 i
    int*   locpre  = (int*)aggbuf;                     // NPAD i (overlay; agg1 rewrites later)

    // Zero cnt (incl padding) + bnsums/bnsc/bnsh
    hipMemsetAsync(cnt, 0, (NPAD + 1024) * sizeof(int), stream);

    // Build CSR (shared by both layers): degree -> 3-phase scan -> fill
    k_degree<<<(NE + 255) / 256, 256, 0, stream>>>(ei, cnt);
    k_scanA<<<NPAD / 1024, 256, 0, stream>>>(cnt, locpre, bsum);
    k_scanB<<<1, 64, 0, stream>>>(bsum, boff);
    k_scanC<<<NPAD / 1024, 256, 0, stream>>>(cnt, locpre, boff, rowptr, cursor, invc);
    k_fill<<<(NE + 255) / 256, 256, 0, stream>>>(ei, cursor, csr_src);

    // Layer 1: aggregate -> fused GEMM -> BN -> ReLU
    k_agg<INC, 2><<<(NN * 64 + 255) / 256, 256, 0, stream>>>(x, rowptr, csr_src, invc, aggbuf);
    k_gemm<128, 128, 256><<<dim3(782, 4), 256, 0, stream>>>(aggbuf, x, W1l, W1r, b1l, h, NN);
    k_bnstats<<<782, 256, 0, stream>>>(h, bnsums);
    k_bnfin<<<1, 256, 0, stream>>>(bnsums, gam1, bet1, bnsc, bnsh);
    k_bnapply<<<(NN * 64 + 255) / 256, 256, 0, stream>>>(h, bnsc, bnsh);

    // Layer 2: aggregate -> fused GEMM
    k_agg<HIDC, 4><<<(NN * 64 + 255) / 256, 256, 0, stream>>>(h, rowptr, csr_src, invc, aggbuf);
    k_gemm<256, 256, 128><<<dim3(782, 2), 256, 0, stream>>>(aggbuf, h, W2l, W2r, b2l, out, NN);
}

// Round 5
// 345.799 us; speedup vs baseline: 3.7592x; 1.5739x over previous
//
#include <hip/hip_runtime.h>

#define NN 50000
#define NPAD 50176   // NN rounded up to 49*1024 (scan int4 loads)
#define MPAD 50048   // 391*128 (GEMM row tiles)
#define NE 800000
#define BN_EPS 1e-5f

typedef __attribute__((ext_vector_type(8))) short bf16x8;
typedef __attribute__((ext_vector_type(4))) float f32x4;

__device__ __forceinline__ void atomAddF(float* p, float v) { unsafeAtomicAdd(p, v); }

__device__ __forceinline__ float bf2f(ushort u) {
    union { uint i; float f; } v; v.i = ((uint)u) << 16; return v.f;
}
__device__ __forceinline__ ushort f2bf(float f) {
    union { uint i; float f; } v; v.f = f;
    uint u = v.i;
    return (ushort)((u + 0x7FFFu + ((u >> 16) & 1u)) >> 16);  // RNE
}

// ---- CSR build: degree ----
__global__ __launch_bounds__(256) void k_degree(const int* __restrict__ ei, int* __restrict__ cnt) {
    unsigned e = blockIdx.x * 256u + threadIdx.x;
    if (e >= (unsigned)NE) return;
    atomicAdd(&cnt[ei[NE + e]], 1);
}

// ---- CSR scan phase A: per-block 1024-elem local scan + block totals ----
__global__ __launch_bounds__(256) void k_scanA(const int* __restrict__ cnt,
                                               int* __restrict__ locpre, int* __restrict__ bsum) {
    const int b = blockIdx.x, t = threadIdx.x;
    const int base = b * 1024 + t * 4;
    int4 v = *reinterpret_cast<const int4*>(&cnt[base]);
    int s = v.x + v.y + v.z + v.w;
    __shared__ int sm[256];
    sm[t] = s;
    __syncthreads();
    for (int off = 1; off < 256; off <<= 1) {
        int y = (t >= off) ? sm[t - off] : 0;
        __syncthreads();
        sm[t] += y;
        __syncthreads();
    }
    int excl = sm[t] - s;
    locpre[base + 0] = excl;
    locpre[base + 1] = excl + v.x;
    locpre[base + 2] = excl + v.x + v.y;
    locpre[base + 3] = excl + v.x + v.y + v.z;
    if (t == 255) bsum[b] = sm[255];
}

// ---- CSR scan phase B: scan 49 block totals (one wave) ----
__global__ __launch_bounds__(64) void k_scanB(const int* __restrict__ bsum, int* __restrict__ boff) {
    const int nb = NPAD / 1024;
    int t = threadIdx.x;
    int v = (t < nb) ? bsum[t] : 0;
    int x = v;
    #pragma unroll
    for (int off = 1; off < 64; off <<= 1) {
        int y = __shfl_up(x, off);
        if (t >= off) x += y;
    }
    boff[t] = x - v;
}

// ---- CSR scan phase C: emit rowptr/cursor/invc ----
__global__ __launch_bounds__(256) void k_scanC(const int* __restrict__ cnt,
                                               const int* __restrict__ locpre,
                                               const int* __restrict__ boff,
                                               int* __restrict__ rowptr, int* __restrict__ cursor,
                                               float* __restrict__ invc) {
    const int b = blockIdx.x, t = threadIdx.x;
    const int off = boff[b];
    const int base = b * 1024 + t * 4;
    #pragma unroll
    for (int k = 0; k < 4; ++k) {
        int i = base + k;
        if (i < NN) {
            int rp = locpre[i] + off;
            rowptr[i] = rp;
            cursor[i] = rp;
            invc[i] = 1.0f / fmaxf((float)cnt[i], 1.0f);
        }
    }
    if (b == 0 && t == 0) rowptr[NN] = NE;
}

// ---- CSR fill ----
__global__ __launch_bounds__(256) void k_fill(const int* __restrict__ ei,
                                              int* __restrict__ cursor, int* __restrict__ csr_src) {
    unsigned e = blockIdx.x * 256u + threadIdx.x;
    if (e >= (unsigned)NE) return;
    int dst = ei[NE + e];
    int pos = atomicAdd(&cursor[dst], 1);
    csr_src[pos] = ei[e];
}

// ---- cast x (fp32) -> xb (bf16), 8 elems/thread ----
__global__ __launch_bounds__(256) void k_castx(const float* __restrict__ x, ushort* __restrict__ xb) {
    unsigned g = blockIdx.x * 256u + threadIdx.x;
    if (g >= (unsigned)NN * 16u) return;
    const float4* p = reinterpret_cast<const float4*>(x) + (size_t)g * 2;
    float4 a = p[0], b = p[1];
    uint4 w;
    w.x = (uint)f2bf(a.x) | ((uint)f2bf(a.y) << 16);
    w.y = (uint)f2bf(a.z) | ((uint)f2bf(a.w) << 16);
    w.z = (uint)f2bf(b.x) | ((uint)f2bf(b.y) << 16);
    w.w = (uint)f2bf(b.z) | ((uint)f2bf(b.w) << 16);
    *reinterpret_cast<uint4*>(&xb[(size_t)g * 8]) = w;
}

// ---- build transposed bf16 weights: Wt1[n][k0..255] = [W1l;W1r], Wt2[n][k0..511] = [W2l;W2r] ----
__global__ __launch_bounds__(256) void k_wt(const float* __restrict__ W1l, const float* __restrict__ W1r,
                                            const float* __restrict__ W2l, const float* __restrict__ W2r,
                                            ushort* __restrict__ Wt1, ushort* __restrict__ Wt2) {
    int g = blockIdx.x * 256 + threadIdx.x;
    if (g < 65536) {
        int n = g >> 8, k = g & 255;
        float v = (k < 128) ? W1l[k * 256 + n] : W1r[(k - 128) * 256 + n];
        Wt1[n * 256 + k] = f2bf(v);
    } else {
        int g2 = g - 65536;
        int n = g2 >> 9, k = g2 & 511;
        float v = (k < 256) ? W2l[k * 128 + n] : W2r[(k - 256) * 128 + n];
        Wt2[n * 512 + k] = f2bf(v);
    }
}

// ---- gather-aggregate (bf16 in/out, fp32 accum); optional fused BN+ReLU on inputs ----
template <int C, bool BN>
__global__ __launch_bounds__(256) void k_agg(const ushort* __restrict__ feat,
                                             const int* __restrict__ rowptr,
                                             const int* __restrict__ csr_src,
                                             const float* __restrict__ invc,
                                             const float* __restrict__ sc,
                                             const float* __restrict__ sh,
                                             ushort* __restrict__ aggb) {
    int gw = (blockIdx.x * 256 + threadIdx.x) >> 6;
    int lane = threadIdx.x & 63;
    if (gw >= NN) return;
    constexpr int V = C / 64;  // 2 or 4
    float fs[V], fh[V];
    if constexpr (BN) {
        #pragma unroll
        for (int i = 0; i < V; ++i) { fs[i] = sc[lane * V + i]; fh[i] = sh[lane * V + i]; }
    }
    float acc[V] = {};
    const int beg = rowptr[gw], end = rowptr[gw + 1];
    for (int e = beg; e < end; ++e) {
        int s = csr_src[e];
        const ushort* p = &feat[(size_t)s * C + lane * V];
        if constexpr (V == 2) {
            uint u = *reinterpret_cast<const uint*>(p);
            float v0 = bf2f((ushort)u), v1 = bf2f((ushort)(u >> 16));
            if constexpr (BN) {
                v0 = fmaxf(fmaf(v0, fs[0], fh[0]), 0.f);
                v1 = fmaxf(fmaf(v1, fs[1], fh[1]), 0.f);
            }
            acc[0] += v0; acc[1] += v1;
        } else {
            uint2 u = *reinterpret_cast<const uint2*>(p);
            float v0 = bf2f((ushort)u.x), v1 = bf2f((ushort)(u.x >> 16));
            float v2 = bf2f((ushort)u.y), v3 = bf2f((ushort)(u.y >> 16));
            if constexpr (BN) {
                v0 = fmaxf(fmaf(v0, fs[0], fh[0]), 0.f);
                v1 = fmaxf(fmaf(v1, fs[1], fh[1]), 0.f);
                v2 = fmaxf(fmaf(v2, fs[2], fh[2]), 0.f);
                v3 = fmaxf(fmaf(v3, fs[3], fh[3]), 0.f);
            }
            acc[0] += v0; acc[1] += v1; acc[2] += v2; acc[3] += v3;
        }
    }
    float ic = invc[gw];
    if constexpr (V == 2) {
        uint o = (uint)f2bf(acc[0] * ic) | ((uint)f2bf(acc[1] * ic) << 16);
        *reinterpret_cast<uint*>(&aggb[(size_t)gw * C + lane * V]) = o;
    } else {
        uint2 o;
        o.x = (uint)f2bf(acc[0] * ic) | ((uint)f2bf(acc[1] * ic) << 16);
        o.y = (uint)f2bf(acc[2] * ic) | ((uint)f2bf(acc[3] * ic) << 16);
        *reinterpret_cast<uint2*>(&aggb[(size_t)gw * C + lane * V]) = o;
    }
}

// ---- MFMA GEMM: out = [A1 | A2] @ Wt^T + bias ----
// 128x128 tile, 4 waves (2x2), 16x16x32 bf16 MFMA, 4x4 frags/wave, BK=32.
// STATS: accumulate per-col sum/sumsq (BN). BNA2: apply BN+ReLU to A2 during staging.
// OUTF32: write fp32 (else bf16).
template <int K1, int K2, int NC, bool STATS, bool BNA2, bool OUTF32>
__global__ __launch_bounds__(256, 2) void k_mm(const ushort* __restrict__ A1,
                                               const ushort* __restrict__ A2,
                                               const ushort* __restrict__ Wt,
                                               const float* __restrict__ bias,
                                               const float* __restrict__ sc,
                                               const float* __restrict__ sh,
                                               float* __restrict__ bnsums,
                                               ushort* __restrict__ outb,
                                               float* __restrict__ outf) {
    constexpr int KT = K1 + K2;
    __shared__ ushort As[128 * 40];  // [row][k], stride 40 (80B, 16B-aligned)
    __shared__ ushort Bs[128 * 40];  // [col][k]
    const int t = threadIdx.x;
    const int lane = t & 63, wid = t >> 6;
    const int wr = wid >> 1, wc = wid & 1;
    const int r0 = blockIdx.x * 128, c0 = blockIdx.y * 128;
    const int lr = lane & 15, lg = lane >> 4;
    f32x4 acc[4][4] = {};

    for (int kt = 0; kt < KT; kt += 32) {
        const ushort* __restrict__ Asrc = (kt < K1) ? A1 : A2;
        const int AK = (kt < K1) ? K1 : K2;
        const int ak = (kt < K1) ? kt : kt - K1;
        // stage A: 128 rows x 32 k (bf16x8 per slot)
        #pragma unroll
        for (int i = 0; i < 2; ++i) {
            int idx = i * 256 + t;
            int row = idx >> 2, kq = idx & 3;
            bf16x8 v = *reinterpret_cast<const bf16x8*>(&Asrc[(size_t)(r0 + row) * AK + ak + kq * 8]);
            if constexpr (BNA2) {
                if (kt >= K1) {
                    int cb = ak + kq * 8;
                    float4 s0 = *reinterpret_cast<const float4*>(&sc[cb]);
                    float4 s1 = *reinterpret_cast<const float4*>(&sc[cb + 4]);
                    float4 h0 = *reinterpret_cast<const float4*>(&sh[cb]);
                    float4 h1 = *reinterpret_cast<const float4*>(&sh[cb + 4]);
                    float fsv[8] = {s0.x, s0.y, s0.z, s0.w, s1.x, s1.y, s1.z, s1.w};
                    float fhv[8] = {h0.x, h0.y, h0.z, h0.w, h1.x, h1.y, h1.z, h1.w};
                    #pragma unroll
                    for (int j = 0; j < 8; ++j) {
                        float f = bf2f((ushort)v[j]);
                        f = fmaxf(fmaf(f, fsv[j], fhv[j]), 0.f);
                        v[j] = (short)f2bf(f);
                    }
                }
            }
            *reinterpret_cast<bf16x8*>(&As[row * 40 + kq * 8]) = v;
        }
        // stage B (Wt is [n][KT] bf16, contiguous along k)
        #pragma unroll
        for (int i = 0; i < 2; ++i) {
            int idx = i * 256 + t;
            int col = idx >> 2, kq = idx & 3;
            *reinterpret_cast<bf16x8*>(&Bs[col * 40 + kq * 8]) =
                *reinterpret_cast<const bf16x8*>(&Wt[(size_t)(c0 + col) * KT + kt + kq * 8]);
        }
        __syncthreads();
        bf16x8 af[4], bfr[4];
        #pragma unroll
        for (int mi = 0; mi < 4; ++mi)
            af[mi] = *reinterpret_cast<bf16x8*>(&As[(wr * 64 + mi * 16 + lr) * 40 + lg * 8]);
        #pragma unroll
        for (int nj = 0; nj < 4; ++nj)
            bfr[nj] = *reinterpret_cast<bf16x8*>(&Bs[(wc * 64 + nj * 16 + lr) * 40 + lg * 8]);
        #pragma unroll
        for (int mi = 0; mi < 4; ++mi)
            #pragma unroll
            for (int nj = 0; nj < 4; ++nj)
                acc[mi][nj] = __builtin_amdgcn_mfma_f32_16x16x32_bf16(af[mi], bfr[nj], acc[mi][nj], 0, 0, 0);
        __syncthreads();
    }

    // epilogue: bias, optional stats, store (mask 16-row blocks past NN)
    #pragma unroll
    for (int nj = 0; nj < 4; ++nj) {
        const int col = c0 + wc * 64 + nj * 16 + lr;
        const float bv = bias[col];
        float s = 0.f, s2 = 0.f;
        #pragma unroll
        for (int mi = 0; mi < 4; ++mi) {
            const int rbase = r0 + wr * 64 + mi * 16;
            if (rbase + 16 > NN) continue;
            #pragma unroll
            for (int reg = 0; reg < 4; ++reg) {
                const int row = rbase + lg * 4 + reg;
                float d = acc[mi][nj][reg] + bv;
                if constexpr (STATS) { s += d; s2 += d * d; }
                if constexpr (OUTF32) outf[(size_t)row * NC + col] = d;
                else outb[(size_t)row * NC + col] = f2bf(d);
            }
        }
        if constexpr (STATS) {
            s += __shfl_xor(s, 16); s += __shfl_xor(s, 32);
            s2 += __shfl_xor(s2, 16); s2 += __shfl_xor(s2, 32);
            if (lane < 16) { atomAddF(&bnsums[col], s); atomAddF(&bnsums[256 + col], s2); }
        }
    }
}

// ---- BN finalize ----
__global__ void k_bnfin(const float* __restrict__ sums, const float* __restrict__ gamma,
                        const float* __restrict__ beta, float* __restrict__ sc,
                        float* __restrict__ sh) {
    int c = threadIdx.x;
    float mu = sums[c] * (1.0f / NN);
    float var = sums[256 + c] * (1.0f / NN) - mu * mu;
    float s = gamma[c] * rsqrtf(var + BN_EPS);
    sc[c] = s;
    sh[c] = beta[c] - mu * s;
}

extern "C" void kernel_launch(void* const* d_in, const int* in_sizes, int n_in,
                              void* d_out, int out_size, void* d_ws, size_t ws_size,
                              hipStream_t stream) {
    const float* x    = (const float*)d_in[0];
    const int*   ei   = (const int*)d_in[1];
    const float* W1l  = (const float*)d_in[2];
    const float* b1l  = (const float*)d_in[3];
    const float* W1r  = (const float*)d_in[4];
    const float* gam1 = (const float*)d_in[5];
    const float* bet1 = (const float*)d_in[6];
    const float* W2l  = (const float*)d_in[7];
    const float* b2l  = (const float*)d_in[8];
    const float* W2r  = (const float*)d_in[9];
    float* out = (float*)d_out;

    char* p = (char*)d_ws;
    ushort* xb   = (ushort*)p; p += (size_t)MPAD * 128 * 2;
    ushort* hb   = (ushort*)p; p += (size_t)MPAD * 256 * 2;
    ushort* aggb = (ushort*)p; p += (size_t)MPAD * 256 * 2;
    ushort* Wt1  = (ushort*)p; p += 256 * 256 * 2;
    ushort* Wt2  = (ushort*)p; p += 128 * 512 * 2;
    int*   cnt    = (int*)p;   p += (size_t)NPAD * 4;
    float* bnsums = (float*)p; p += 512 * 4;
    float* bnsc   = (float*)p; p += 256 * 4;
    float* bnsh   = (float*)p; p += 256 * 4;
    float* invc   = (float*)p; p += (size_t)NPAD * 4;
    int*   rowptr = (int*)p;   p += (size_t)(NPAD + 4) * 4;
    int*   cursor = (int*)p;   p += (size_t)NPAD * 4;
    int*   csr_src= (int*)p;   p += (size_t)NE * 4;
    int*   bsum   = (int*)p;   p += 64 * 4;
    int*   boff   = (int*)p;
    int*   locpre = (int*)aggb;  // overlay: consumed by k_scanC before aggb written

    // zero cnt + bnsums/bnsc/bnsh (contiguous)
    hipMemsetAsync(cnt, 0, (size_t)NPAD * 4 + 4096, stream);

    // CSR build
    k_degree<<<(NE + 255) / 256, 256, 0, stream>>>(ei, cnt);
    k_scanA<<<NPAD / 1024, 256, 0, stream>>>(cnt, locpre, bsum);
    k_scanB<<<1, 64, 0, stream>>>(bsum, boff);
    k_scanC<<<NPAD / 1024, 256, 0, stream>>>(cnt, locpre, boff, rowptr, cursor, invc);
    k_fill<<<(NE + 255) / 256, 256, 0, stream>>>(ei, cursor, csr_src);

    // precompute bf16 tensors
    k_castx<<<(NN * 16 + 255) / 256, 256, 0, stream>>>(x, xb);
    k_wt<<<512, 256, 0, stream>>>(W1l, W1r, W2l, W2r, Wt1, Wt2);

    // Layer 1: agg(x) -> GEMM(+bias, fused BN stats) -> bnfin
    k_agg<128, false><<<(NN * 64 + 255) / 256, 256, 0, stream>>>(xb, rowptr, csr_src, invc, nullptr, nullptr, aggb);
    k_mm<128, 128, 256, true, false, false><<<dim3(391, 2), 256, 0, stream>>>(
        aggb, xb, Wt1, b1l, nullptr, nullptr, bnsums, hb, nullptr);
    k_bnfin<<<1, 256, 0, stream>>>(bnsums, gam1, bet1, bnsc, bnsh);

    // Layer 2: agg(relu(bn(h))) -> GEMM(+bias) -> out (BN+ReLU fused into both readers)
    k_agg<256, true><<<(NN * 64 + 255) / 256, 256, 0, stream>>>(hb, rowptr, csr_src, invc, bnsc, bnsh, aggb);
    k_mm<256, 256, 128, false, true, true><<<dim3(391, 1), 256, 0, stream>>>(
        aggb, hb, Wt2, b2l, bnsc, bnsh, nullptr, nullptr, out);
}

// Round 6
// 246.223 us; speedup vs baseline: 5.2795x; 1.4044x over previous
//
#include <hip/hip_runtime.h>

#define NN 50000
#define NPAD 50176   // NN rounded up to 49*1024 (scan int4 loads)
#define MPAD 50048   // 391*128 (GEMM row tiles)
#define NE 800000
#define BN_EPS 1e-5f

typedef __attribute__((ext_vector_type(8))) short bf16x8;
typedef __attribute__((ext_vector_type(4))) float f32x4;

__device__ __forceinline__ void atomAddF(float* p, float v) { unsafeAtomicAdd(p, v); }

__device__ __forceinline__ float bf2f(ushort u) {
    union { uint i; float f; } v; v.i = ((uint)u) << 16; return v.f;
}
__device__ __forceinline__ ushort f2bf(float f) {
    union { uint i; float f; } v; v.f = f;
    uint u = v.i;
    return (ushort)((u + 0x7FFFu + ((u >> 16) & 1u)) >> 16);  // RNE
}

// ---- CSR build: degree ----
__global__ __launch_bounds__(256) void k_degree(const int* __restrict__ ei, int* __restrict__ cnt) {
    unsigned e = blockIdx.x * 256u + threadIdx.x;
    if (e >= (unsigned)NE) return;
    atomicAdd(&cnt[ei[NE + e]], 1);
}

// ---- CSR scan phase A ----
__global__ __launch_bounds__(256) void k_scanA(const int* __restrict__ cnt,
                                               int* __restrict__ locpre, int* __restrict__ bsum) {
    const int b = blockIdx.x, t = threadIdx.x;
    const int base = b * 1024 + t * 4;
    int4 v = *reinterpret_cast<const int4*>(&cnt[base]);
    int s = v.x + v.y + v.z + v.w;
    __shared__ int sm[256];
    sm[t] = s;
    __syncthreads();
    for (int off = 1; off < 256; off <<= 1) {
        int y = (t >= off) ? sm[t - off] : 0;
        __syncthreads();
        sm[t] += y;
        __syncthreads();
    }
    int excl = sm[t] - s;
    locpre[base + 0] = excl;
    locpre[base + 1] = excl + v.x;
    locpre[base + 2] = excl + v.x + v.y;
    locpre[base + 3] = excl + v.x + v.y + v.z;
    if (t == 255) bsum[b] = sm[255];
}

// ---- CSR scan phase B ----
__global__ __launch_bounds__(64) void k_scanB(const int* __restrict__ bsum, int* __restrict__ boff) {
    const int nb = NPAD / 1024;
    int t = threadIdx.x;
    int v = (t < nb) ? bsum[t] : 0;
    int x = v;
    #pragma unroll
    for (int off = 1; off < 64; off <<= 1) {
        int y = __shfl_up(x, off);
        if (t >= off) x += y;
    }
    boff[t] = x - v;
}

// ---- CSR scan phase C ----
__global__ __launch_bounds__(256) void k_scanC(const int* __restrict__ cnt,
                                               const int* __restrict__ locpre,
                                               const int* __restrict__ boff,
                                               int* __restrict__ rowptr, int* __restrict__ cursor,
                                               float* __restrict__ invc) {
    const int b = blockIdx.x, t = threadIdx.x;
    const int off = boff[b];
    const int base = b * 1024 + t * 4;
    #pragma unroll
    for (int k = 0; k < 4; ++k) {
        int i = base + k;
        if (i < NN) {
            int rp = locpre[i] + off;
            rowptr[i] = rp;
            cursor[i] = rp;
            invc[i] = 1.0f / fmaxf((float)cnt[i], 1.0f);
        }
    }
    if (b == 0 && t == 0) rowptr[NN] = NE;
}

// ---- CSR fill ----
__global__ __launch_bounds__(256) void k_fill(const int* __restrict__ ei,
                                              int* __restrict__ cursor, int* __restrict__ csr_src) {
    unsigned e = blockIdx.x * 256u + threadIdx.x;
    if (e >= (unsigned)NE) return;
    int dst = ei[NE + e];
    int pos = atomicAdd(&cursor[dst], 1);
    csr_src[pos] = ei[e];
}

// ---- cast x (fp32) -> xb (bf16) ----
__global__ __launch_bounds__(256) void k_castx(const float* __restrict__ x, ushort* __restrict__ xb) {
    unsigned g = blockIdx.x * 256u + threadIdx.x;
    if (g >= (unsigned)NN * 16u) return;
    const float4* p = reinterpret_cast<const float4*>(x) + (size_t)g * 2;
    float4 a = p[0], b = p[1];
    uint4 w;
    w.x = (uint)f2bf(a.x) | ((uint)f2bf(a.y) << 16);
    w.y = (uint)f2bf(a.z) | ((uint)f2bf(a.w) << 16);
    w.z = (uint)f2bf(b.x) | ((uint)f2bf(b.y) << 16);
    w.w = (uint)f2bf(b.z) | ((uint)f2bf(b.w) << 16);
    *reinterpret_cast<uint4*>(&xb[(size_t)g * 8]) = w;
}

// ---- transposed bf16 weights ----
// Wt1[n][k], n<256, k<256: [W1l; W1r] stacked along k.
// Wt2[n][k], n<256, k<256: cols n<128 from W2l, n>=128 from W2r (both 256x128).
__global__ __launch_bounds__(256) void k_wt(const float* __restrict__ W1l, const float* __restrict__ W1r,
                                            const float* __restrict__ W2l, const float* __restrict__ W2r,
                                            ushort* __restrict__ Wt1, ushort* __restrict__ Wt2) {
    int g = blockIdx.x * 256 + threadIdx.x;
    if (g < 65536) {
        int n = g >> 8, k = g & 255;
        float v = (k < 128) ? W1l[k * 256 + n] : W1r[(k - 128) * 256 + n];
        Wt1[n * 256 + k] = f2bf(v);
    } else {
        int g2 = g - 65536;
        int n = g2 >> 8, k = g2 & 255;
        float v = (n < 128) ? W2l[k * 128 + n] : W2r[k * 128 + (n - 128)];
        Wt2[n * 256 + k] = f2bf(v);
    }
}

// ---- gather-aggregate over 128-ch bf16 rows, 4-way edge-parallel per wave ----
// One node per wave: 16 lanes x uint4 cover the 256B row; 4 lane-groups stride the
// edge list; shfl_xor(16/32) reduce. FINAL: out = acc*ic + z + bias (fp32); else bf16 agg.
template <bool FINAL>
__global__ __launch_bounds__(256) void k_agg128(const ushort* __restrict__ feat,
                                                const int* __restrict__ rowptr,
                                                const int* __restrict__ csr_src,
                                                const float* __restrict__ invc,
                                                const float* __restrict__ z,
                                                const float* __restrict__ bias,
                                                ushort* __restrict__ aggb,
                                                float* __restrict__ outf) {
    int gw = (blockIdx.x * 256 + threadIdx.x) >> 6;
    int lane = threadIdx.x & 63;
    if (gw >= NN) return;
    const int grp = lane >> 4, sl = lane & 15;
    const int beg = rowptr[gw], end = rowptr[gw + 1];
    float acc[8] = {};
    for (int e = beg + grp; e < end; e += 4) {
        int s = csr_src[e];
        uint4 u = *reinterpret_cast<const uint4*>(&feat[(size_t)s * 128 + sl * 8]);
        acc[0] += bf2f((ushort)u.x); acc[1] += bf2f((ushort)(u.x >> 16));
        acc[2] += bf2f((ushort)u.y); acc[3] += bf2f((ushort)(u.y >> 16));
        acc[4] += bf2f((ushort)u.z); acc[5] += bf2f((ushort)(u.z >> 16));
        acc[6] += bf2f((ushort)u.w); acc[7] += bf2f((ushort)(u.w >> 16));
    }
    #pragma unroll
    for (int i = 0; i < 8; ++i) {
        acc[i] += __shfl_xor(acc[i], 16);
        acc[i] += __shfl_xor(acc[i], 32);
    }
    if (grp == 0) {
        const float ic = invc[gw];
        if constexpr (FINAL) {
            const float* zp = &z[(size_t)gw * 128 + sl * 8];
            float4 z0 = *reinterpret_cast<const float4*>(zp);
            float4 z1 = *reinterpret_cast<const float4*>(zp + 4);
            float4 b0 = *reinterpret_cast<const float4*>(&bias[sl * 8]);
            float4 b1 = *reinterpret_cast<const float4*>(&bias[sl * 8 + 4]);
            float4 o0, o1;
            o0.x = fmaf(acc[0], ic, z0.x + b0.x);
            o0.y = fmaf(acc[1], ic, z0.y + b0.y);
            o0.z = fmaf(acc[2], ic, z0.z + b0.z);
            o0.w = fmaf(acc[3], ic, z0.w + b0.w);
            o1.x = fmaf(acc[4], ic, z1.x + b1.x);
            o1.y = fmaf(acc[5], ic, z1.y + b1.y);
            o1.z = fmaf(acc[6], ic, z1.z + b1.z);
            o1.w = fmaf(acc[7], ic, z1.w + b1.w);
            float* op = &outf[(size_t)gw * 128 + sl * 8];
            *reinterpret_cast<float4*>(op) = o0;
            *reinterpret_cast<float4*>(op + 4) = o1;
        } else {
            uint4 o;
            o.x = (uint)f2bf(acc[0] * ic) | ((uint)f2bf(acc[1] * ic) << 16);
            o.y = (uint)f2bf(acc[2] * ic) | ((uint)f2bf(acc[3] * ic) << 16);
            o.z = (uint)f2bf(acc[4] * ic) | ((uint)f2bf(acc[5] * ic) << 16);
            o.w = (uint)f2bf(acc[6] * ic) | ((uint)f2bf(acc[7] * ic) << 16);
            *reinterpret_cast<uint4*>(&aggb[(size_t)gw * 128 + sl * 8]) = o;
        }
    }
}

// ---- MFMA GEMM: out = [A1 | A2] @ Wt^T (+bias) ----
// 128x128 tile, 4 waves (2x2), 16x16x32 bf16 MFMA, 4x4 frags/wave, BK=32.
// STATS: per-col sum/sumsq atomics. BN1: BN+ReLU applied to A1 during staging.
// OUTMODE 0: bf16 out (NC cols) + bias. OUTMODE 1: cols<128 -> bf16 outb, cols>=128 -> fp32 outf, no bias.
template <int K1, int K2, int NC, bool STATS, bool BN1, int OUTMODE>
__global__ __launch_bounds__(256, 2) void k_mm(const ushort* __restrict__ A1,
                                               const ushort* __restrict__ A2,
                                               const ushort* __restrict__ Wt,
                                               const float* __restrict__ bias,
                                               const float* __restrict__ sc,
                                               const float* __restrict__ sh,
                                               float* __restrict__ bnsums,
                                               ushort* __restrict__ outb,
                                               float* __restrict__ outf) {
    constexpr int KT = K1 + K2;
    __shared__ ushort As[128 * 40];
    __shared__ ushort Bs[128 * 40];
    const int t = threadIdx.x;
    const int lane = t & 63, wid = t >> 6;
    const int wr = wid >> 1, wc = wid & 1;
    const int r0 = blockIdx.x * 128, c0 = blockIdx.y * 128;
    const int lr = lane & 15, lg = lane >> 4;
    f32x4 acc[4][4] = {};

    for (int kt = 0; kt < KT; kt += 32) {
        const ushort* __restrict__ Asrc = (kt < K1) ? A1 : A2;
        const int AK = (kt < K1) ? K1 : K2;
        const int ak = (kt < K1) ? kt : kt - K1;
        #pragma unroll
        for (int i = 0; i < 2; ++i) {
            int idx = i * 256 + t;
            int row = idx >> 2, kq = idx & 3;
            bf16x8 v = *reinterpret_cast<const bf16x8*>(&Asrc[(size_t)(r0 + row) * AK + ak + kq * 8]);
            if constexpr (BN1) {
                if (kt < K1) {
                    int cb = ak + kq * 8;
                    float4 s0 = *reinterpret_cast<const float4*>(&sc[cb]);
                    float4 s1 = *reinterpret_cast<const float4*>(&sc[cb + 4]);
                    float4 h0 = *reinterpret_cast<const float4*>(&sh[cb]);
                    float4 h1 = *reinterpret_cast<const float4*>(&sh[cb + 4]);
                    float fsv[8] = {s0.x, s0.y, s0.z, s0.w, s1.x, s1.y, s1.z, s1.w};
                    float fhv[8] = {h0.x, h0.y, h0.z, h0.w, h1.x, h1.y, h1.z, h1.w};
                    #pragma unroll
                    for (int j = 0; j < 8; ++j) {
                        float f = bf2f((ushort)v[j]);
                        f = fmaxf(fmaf(f, fsv[j], fhv[j]), 0.f);
                        v[j] = (short)f2bf(f);
                    }
                }
            }
            *reinterpret_cast<bf16x8*>(&As[row * 40 + kq * 8]) = v;
        }
        #pragma unroll
        for (int i = 0; i < 2; ++i) {
            int idx = i * 256 + t;
            int col = idx >> 2, kq = idx & 3;
            *reinterpret_cast<bf16x8*>(&Bs[col * 40 + kq * 8]) =
                *reinterpret_cast<const bf16x8*>(&Wt[(size_t)(c0 + col) * KT + kt + kq * 8]);
        }
        __syncthreads();
        bf16x8 af[4], bfr[4];
        #pragma unroll
        for (int mi = 0; mi < 4; ++mi)
            af[mi] = *reinterpret_cast<bf16x8*>(&As[(wr * 64 + mi * 16 + lr) * 40 + lg * 8]);
        #pragma unroll
        for (int nj = 0; nj < 4; ++nj)
            bfr[nj] = *reinterpret_cast<bf16x8*>(&Bs[(wc * 64 + nj * 16 + lr) * 40 + lg * 8]);
        #pragma unroll
        for (int mi = 0; mi < 4; ++mi)
            #pragma unroll
            for (int nj = 0; nj < 4; ++nj)
                acc[mi][nj] = __builtin_amdgcn_mfma_f32_16x16x32_bf16(af[mi], bfr[nj], acc[mi][nj], 0, 0, 0);
        __syncthreads();
    }

    #pragma unroll
    for (int nj = 0; nj < 4; ++nj) {
        const int col = c0 + wc * 64 + nj * 16 + lr;
        float bv = 0.f;
        if constexpr (OUTMODE == 0) bv = bias[col];
        float s = 0.f, s2 = 0.f;
        #pragma unroll
        for (int mi = 0; mi < 4; ++mi) {
            const int rbase = r0 + wr * 64 + mi * 16;
            if (rbase + 16 > NN) continue;
            #pragma unroll
            for (int reg = 0; reg < 4; ++reg) {
                const int row = rbase + lg * 4 + reg;
                float d = acc[mi][nj][reg] + bv;
                if constexpr (STATS) { s += d; s2 += d * d; }
                if constexpr (OUTMODE == 0) {
                    outb[(size_t)row * NC + col] = f2bf(d);
                } else {
                    if (col < 128) outb[(size_t)row * 128 + col] = f2bf(d);
                    else outf[(size_t)row * 128 + (col - 128)] = d;
                }
            }
        }
        if constexpr (STATS) {
            s += __shfl_xor(s, 16); s += __shfl_xor(s, 32);
            s2 += __shfl_xor(s2, 16); s2 += __shfl_xor(s2, 32);
            if (lane < 16) { atomAddF(&bnsums[col], s); atomAddF(&bnsums[256 + col], s2); }
        }
    }
}

// ---- BN finalize ----
__global__ void k_bnfin(const float* __restrict__ sums, const float* __restrict__ gamma,
                        const float* __restrict__ beta, float* __restrict__ sc,
                        float* __restrict__ sh) {
    int c = threadIdx.x;
    float mu = sums[c] * (1.0f / NN);
    float var = sums[256 + c] * (1.0f / NN) - mu * mu;
    float s = gamma[c] * rsqrtf(var + BN_EPS);
    sc[c] = s;
    sh[c] = beta[c] - mu * s;
}

extern "C" void kernel_launch(void* const* d_in, const int* in_sizes, int n_in,
                              void* d_out, int out_size, void* d_ws, size_t ws_size,
                              hipStream_t stream) {
    const float* x    = (const float*)d_in[0];
    const int*   ei   = (const int*)d_in[1];
    const float* W1l  = (const float*)d_in[2];
    const float* b1l  = (const float*)d_in[3];
    const float* W1r  = (const float*)d_in[4];
    const float* gam1 = (const float*)d_in[5];
    const float* bet1 = (const float*)d_in[6];
    const float* W2l  = (const float*)d_in[7];
    const float* b2l  = (const float*)d_in[8];
    const float* W2r  = (const float*)d_in[9];
    float* out = (float*)d_out;

    char* p = (char*)d_ws;
    ushort* xb   = (ushort*)p; p += (size_t)MPAD * 128 * 2;
    ushort* hb   = (ushort*)p; p += (size_t)MPAD * 256 * 2;
    ushort* aggb = (ushort*)p; p += (size_t)MPAD * 128 * 2;
    ushort* y2b  = (ushort*)p; p += (size_t)MPAD * 128 * 2;
    float*  zf   = (float*)p;  p += (size_t)MPAD * 128 * 4;
    ushort* Wt1  = (ushort*)p; p += 256 * 256 * 2;
    ushort* Wt2  = (ushort*)p; p += 256 * 256 * 2;
    int*   cnt    = (int*)p;   p += (size_t)NPAD * 4;
    float* bnsums = (float*)p; p += 512 * 4;
    float* bnsc   = (float*)p; p += 256 * 4;
    float* bnsh   = (float*)p; p += 256 * 4;
    float* invc   = (float*)p; p += (size_t)NPAD * 4;
    int*   rowptr = (int*)p;   p += (size_t)(NPAD + 4) * 4;
    int*   cursor = (int*)p;   p += (size_t)NPAD * 4;
    int*   csr_src= (int*)p;   p += (size_t)NE * 4;
    int*   bsum   = (int*)p;   p += 64 * 4;
    int*   boff   = (int*)p;
    int*   locpre = (int*)aggb;  // overlay: consumed by k_scanC before aggb written

    hipMemsetAsync(cnt, 0, (size_t)NPAD * 4 + 4096, stream);

    // CSR build
    k_degree<<<(NE + 255) / 256, 256, 0, stream>>>(ei, cnt);
    k_scanA<<<NPAD / 1024, 256, 0, stream>>>(cnt, locpre, bsum);
    k_scanB<<<1, 64, 0, stream>>>(bsum, boff);
    k_scanC<<<NPAD / 1024, 256, 0, stream>>>(cnt, locpre, boff, rowptr, cursor, invc);
    k_fill<<<(NE + 255) / 256, 256, 0, stream>>>(ei, cursor, csr_src);

    // bf16 precompute
    k_castx<<<(NN * 16 + 255) / 256, 256, 0, stream>>>(x, xb);
    k_wt<<<512, 256, 0, stream>>>(W1l, W1r, W2l, W2r, Wt1, Wt2);

    // Layer 1: agg(x) -> GEMM [agg|x]@Wt1 (+bias, BN stats) -> bnfin
    k_agg128<false><<<12500, 256, 0, stream>>>(xb, rowptr, csr_src, invc, nullptr, nullptr, aggb, nullptr);
    k_mm<128, 128, 256, true, false, 0><<<dim3(391, 2), 256, 0, stream>>>(
        aggb, xb, Wt1, b1l, nullptr, nullptr, bnsums, hb, nullptr);
    k_bnfin<<<1, 256, 0, stream>>>(bnsums, gam1, bet1, bnsc, bnsh);

    // Layer 2 (swapped): [y2|z] = relu(bn(h)) @ [W2l|W2r]; out = mean(y2[src]) + z + b
    k_mm<256, 0, 256, false, true, 1><<<dim3(391, 2), 256, 0, stream>>>(
        hb, nullptr, Wt2, nullptr, bnsc, bnsh, nullptr, y2b, zf);
    k_agg128<true><<<12500, 256, 0, stream>>>(y2b, rowptr, csr_src, invc, zf, b2l, nullptr, out);
}